// Round 1
// baseline (451.424 us; speedup 1.0000x reference)
//
#include <hip/hip_runtime.h>

// WeightedAggEdge: node_feat = h@Wn^T; per-edge segment-softmax attention
// over fc_e(e) grouped by src node; outputs (node_feat, gamma * e_w).
//
// Algebraic restructure:
//   logit a_i = dot(e_i, v) + s_n[src_i],  v = We^T @ Wa[:,0:64],
//   s_n[n] = dot(Wa[:,64:128], node_feat[n])
//   gamma_i = exp(lr_i) / denom[src_i]  (shift-invariant, no segment-max pass)
//   e_weighted_i = gamma_i * (e_i @ We^T)   (computed once, fused)

constexpr int kNodes   = 50000;
constexpr int kEdges   = 800000;
constexpr int kNodeIn  = 128;
constexpr int kNodeOut = 64;
constexpr int kEdgeIn  = 64;
constexpr int kEdgeOut = 64;
#define NEG_SLOPE 0.01f

// ws layout (floats):
//   [0, 64)                      v = We^T @ Wa_e
//   [64, 64+kNodes)              s_n
//   [64+kNodes, 64+2k)           denom
//   [64+2*kNodes, +kEdges)       ex (exp of leaky logit per edge)

__global__ void k0_prep(const float* __restrict__ We, const float* __restrict__ Wa,
                        float* __restrict__ v) {
    int k = threadIdx.x;
    if (k < kEdgeIn) {
        float acc = 0.f;
        #pragma unroll
        for (int c = 0; c < kEdgeOut; ++c) acc = fmaf(Wa[c], We[c * kEdgeIn + k], acc);
        v[k] = acc;
    }
}

__global__ __launch_bounds__(256) void k1_nodes(
    const float* __restrict__ h, const float* __restrict__ Wn,
    const float* __restrict__ Wa, float* __restrict__ node_feat,
    float* __restrict__ s_n, float* __restrict__ denom) {
    int n = blockIdx.x * 256 + threadIdx.x;
    if (n >= kNodes) return;
    float acc[kNodeOut];
    #pragma unroll
    for (int c = 0; c < kNodeOut; ++c) acc[c] = 0.f;
    const float4* h4 = reinterpret_cast<const float4*>(h + (size_t)n * kNodeIn);
    #pragma unroll 1
    for (int kq = 0; kq < kNodeIn / 4; ++kq) {
        float4 t = h4[kq];
        #pragma unroll
        for (int c = 0; c < kNodeOut; ++c) {
            const float* w = Wn + c * kNodeIn + kq * 4;  // wave-uniform -> s_load
            acc[c] = fmaf(t.x, w[0], acc[c]);
            acc[c] = fmaf(t.y, w[1], acc[c]);
            acc[c] = fmaf(t.z, w[2], acc[c]);
            acc[c] = fmaf(t.w, w[3], acc[c]);
        }
    }
    float sn = 0.f;
    #pragma unroll
    for (int c = 0; c < kNodeOut; ++c) sn = fmaf(Wa[64 + c], acc[c], sn);
    float4* out4 = reinterpret_cast<float4*>(node_feat + (size_t)n * kNodeOut);
    #pragma unroll
    for (int q = 0; q < kNodeOut / 4; ++q) {
        float4 o;
        o.x = acc[4 * q]; o.y = acc[4 * q + 1]; o.z = acc[4 * q + 2]; o.w = acc[4 * q + 3];
        out4[q] = o;
    }
    s_n[n] = sn;
    denom[n] = 0.f;
}

__global__ __launch_bounds__(256) void k2_logits(
    const float* __restrict__ e, const int* __restrict__ src,
    const float* __restrict__ v, const float* __restrict__ s_n,
    float* __restrict__ denom, float* __restrict__ ex) {
    int i = blockIdx.x * 256 + threadIdx.x;
    if (i >= kEdges) return;
    const float4* e4 = reinterpret_cast<const float4*>(e + (size_t)i * kEdgeIn);
    float av = 0.f;
    #pragma unroll
    for (int q = 0; q < kEdgeIn / 4; ++q) {
        float4 t = e4[q];
        av = fmaf(t.x, v[4 * q],     av);
        av = fmaf(t.y, v[4 * q + 1], av);
        av = fmaf(t.z, v[4 * q + 2], av);
        av = fmaf(t.w, v[4 * q + 3], av);
    }
    int s = src[i];
    float a = av + s_n[s];
    float lr = (a >= 0.f) ? a : NEG_SLOPE * a;
    float xe = __expf(lr);
    ex[i] = xe;
    atomicAdd(denom + s, xe);
}

__global__ __launch_bounds__(256) void k4_out(
    const float* __restrict__ e, const int* __restrict__ src,
    const float* __restrict__ We, const float* __restrict__ denom,
    const float* __restrict__ ex, float* __restrict__ oute) {
    int i = blockIdx.x * 256 + threadIdx.x;
    if (i >= kEdges) return;
    float es[kEdgeIn];
    const float4* e4 = reinterpret_cast<const float4*>(e + (size_t)i * kEdgeIn);
    #pragma unroll
    for (int q = 0; q < kEdgeIn / 4; ++q) {
        float4 t = e4[q];
        es[4 * q] = t.x; es[4 * q + 1] = t.y; es[4 * q + 2] = t.z; es[4 * q + 3] = t.w;
    }
    int s = src[i];
    float gamma = ex[i] / denom[s];
    float4* o4 = reinterpret_cast<float4*>(oute + (size_t)i * kEdgeOut);
    #pragma unroll 1
    for (int cb = 0; cb < kEdgeOut; cb += 8) {
        float acc[8];
        #pragma unroll
        for (int cc = 0; cc < 8; ++cc) acc[cc] = 0.f;
        #pragma unroll
        for (int k = 0; k < kEdgeIn; ++k) {
            #pragma unroll
            for (int cc = 0; cc < 8; ++cc)
                acc[cc] = fmaf(es[k], We[(cb + cc) * kEdgeIn + k], acc[cc]);  // uniform -> s_load
        }
        float4 o;
        o.x = gamma * acc[0]; o.y = gamma * acc[1]; o.z = gamma * acc[2]; o.w = gamma * acc[3];
        o4[cb / 4] = o;
        o.x = gamma * acc[4]; o.y = gamma * acc[5]; o.z = gamma * acc[6]; o.w = gamma * acc[7];
        o4[cb / 4 + 1] = o;
    }
}

extern "C" void kernel_launch(void* const* d_in, const int* in_sizes, int n_in,
                              void* d_out, int out_size, void* d_ws, size_t ws_size,
                              hipStream_t stream) {
    const float* h   = (const float*)d_in[0];
    const float* e   = (const float*)d_in[1];
    const float* Wn  = (const float*)d_in[2];
    const float* We  = (const float*)d_in[3];
    const float* Wa  = (const float*)d_in[4];
    const int*   src = (const int*)d_in[5];

    float* node_feat = (float*)d_out;
    float* oute      = (float*)d_out + (size_t)kNodes * kNodeOut;

    float* ws    = (float*)d_ws;
    float* v     = ws;
    float* s_n   = ws + 64;
    float* denom = ws + 64 + kNodes;
    float* ex    = ws + 64 + 2 * kNodes;

    k0_prep<<<1, 64, 0, stream>>>(We, Wa, v);
    k1_nodes<<<(kNodes + 255) / 256, 256, 0, stream>>>(h, Wn, Wa, node_feat, s_n, denom);
    k2_logits<<<kEdges / 256, 256, 0, stream>>>(e, src, v, s_n, denom, ex);
    k4_out<<<kEdges / 256, 256, 0, stream>>>(e, src, We, denom, ex, oute);
}

// Round 2
// 290.445 us; speedup vs baseline: 1.5543x; 1.5543x over previous
//
#include <hip/hip_runtime.h>

// WeightedAggEdge: node_feat = h@Wn^T; per-edge segment-softmax attention
// over fc_e(e) grouped by src node; outputs (node_feat, gamma * e_w).
//
// Algebraic restructure:
//   logit a_i = dot(e_i, v) + s_n[src_i],  v = We^T @ Wa[:,0:64],
//   s_n[n] = dot(Wa[:,64:128], node_feat[n])
//   gamma_i = exp(lr_i) / denom[src_i]  (shift-invariant, no segment-max pass)
//   e_weighted_i = gamma_i * (e_i @ We^T)   -- bf16 MFMA (threshold 1.08e-1 allows)

constexpr int kNodes   = 50000;
constexpr int kEdges   = 800000;
constexpr int kNodeIn  = 128;
constexpr int kNodeOut = 64;
constexpr int kEdgeIn  = 64;
constexpr int kEdgeOut = 64;
#define NEG_SLOPE 0.01f

typedef __attribute__((ext_vector_type(8))) short short8;   // 8 bf16 = 4 VGPRs
typedef __attribute__((ext_vector_type(4))) float f32x4;

// ws layout (float index):
//   [0, 64)              v = We^T @ Wa_e
//   [64, 50064)          s_n
//   [50064, 100064)      denom
//   [100064, 900064)     ex  (k2: exp of leaky logit; k3 overwrites in-place with gamma)
//   [900064, +2048)      We_bf16 (4096 shorts, row-major [out][in])
constexpr int kOffV     = 0;
constexpr int kOffSn    = 64;
constexpr int kOffDenom = 50064;
constexpr int kOffEx    = 100064;
constexpr int kOffWeB   = 900064;  // as short*, 16B-aligned

__device__ inline short f2bf(float x) {
    union { float f; unsigned u; } v; v.f = x;
    unsigned r = v.u + 0x7FFFu + ((v.u >> 16) & 1u);  // RNE
    return (short)(r >> 16);
}

__global__ void k0_prep(const float* __restrict__ We, const float* __restrict__ Wa,
                        float* __restrict__ v, short* __restrict__ Web) {
    int t = threadIdx.x;
    if (t < kEdgeIn) {
        float acc = 0.f;
        #pragma unroll
        for (int c = 0; c < kEdgeOut; ++c) acc = fmaf(Wa[c], We[c * kEdgeIn + t], acc);
        v[t] = acc;
    }
    #pragma unroll
    for (int i = 0; i < (kEdgeOut * kEdgeIn) / 256; ++i)
        Web[i * 256 + t] = f2bf(We[i * 256 + t]);
}

__global__ __launch_bounds__(256) void k1_nodes(
    const float* __restrict__ h, const float* __restrict__ Wn,
    const float* __restrict__ Wa, float* __restrict__ node_feat,
    float* __restrict__ s_n, float* __restrict__ denom) {
    int n = blockIdx.x * 256 + threadIdx.x;
    if (n >= kNodes) return;
    float acc[kNodeOut];
    #pragma unroll
    for (int c = 0; c < kNodeOut; ++c) acc[c] = 0.f;
    const float4* h4 = reinterpret_cast<const float4*>(h + (size_t)n * kNodeIn);
    #pragma unroll 1
    for (int kq = 0; kq < kNodeIn / 4; ++kq) {
        float4 t = h4[kq];
        #pragma unroll
        for (int c = 0; c < kNodeOut; ++c) {
            const float* w = Wn + c * kNodeIn + kq * 4;  // wave-uniform -> s_load
            acc[c] = fmaf(t.x, w[0], acc[c]);
            acc[c] = fmaf(t.y, w[1], acc[c]);
            acc[c] = fmaf(t.z, w[2], acc[c]);
            acc[c] = fmaf(t.w, w[3], acc[c]);
        }
    }
    float sn = 0.f;
    #pragma unroll
    for (int c = 0; c < kNodeOut; ++c) sn = fmaf(Wa[64 + c], acc[c], sn);
    float4* out4 = reinterpret_cast<float4*>(node_feat + (size_t)n * kNodeOut);
    #pragma unroll
    for (int q = 0; q < kNodeOut / 4; ++q) {
        float4 o;
        o.x = acc[4 * q]; o.y = acc[4 * q + 1]; o.z = acc[4 * q + 2]; o.w = acc[4 * q + 3];
        out4[q] = o;
    }
    s_n[n] = sn;
    denom[n] = 0.f;
}

__global__ __launch_bounds__(256) void k2_logits(
    const float* __restrict__ e, const int* __restrict__ src,
    const float* __restrict__ v, const float* __restrict__ s_n,
    float* __restrict__ denom, float* __restrict__ ex) {
    int i = blockIdx.x * 256 + threadIdx.x;
    if (i >= kEdges) return;
    const float4* e4 = reinterpret_cast<const float4*>(e + (size_t)i * kEdgeIn);
    float av = 0.f;
    #pragma unroll
    for (int q = 0; q < kEdgeIn / 4; ++q) {
        float4 t = e4[q];
        av = fmaf(t.x, v[4 * q],     av);
        av = fmaf(t.y, v[4 * q + 1], av);
        av = fmaf(t.z, v[4 * q + 2], av);
        av = fmaf(t.w, v[4 * q + 3], av);
    }
    int s = src[i];
    float a = av + s_n[s];
    float lr = (a >= 0.f) ? a : NEG_SLOPE * a;
    float xe = __expf(lr);
    ex[i] = xe;
    atomicAdd(denom + s, xe);
}

// ex[i] <- gamma_i = ex[i] / denom[src[i]]   (in-place; k2 rewrites ex each call)
__global__ __launch_bounds__(256) void k3_gamma(
    const int* __restrict__ src, const float* __restrict__ denom,
    float* __restrict__ ex) {
    int i = blockIdx.x * 256 + threadIdx.x;
    if (i >= kEdges) return;
    ex[i] = ex[i] / denom[src[i]];
}

// e_weighted = gamma * (e @ We^T) via bf16 MFMA.
// Per wave: 64 edges (4 M-tiles of 16), full N=64 (4 col-tiles), K=64 (2 k-tiles).
__global__ __launch_bounds__(256) void k4_mfma(
    const float* __restrict__ e, const short* __restrict__ Web,
    const float* __restrict__ gamma, float* __restrict__ oute) {
    const int wave = threadIdx.x >> 6;
    const int lane = threadIdx.x & 63;
    const int l15  = lane & 15;
    const int lhi  = lane >> 4;
    const long base = (long)blockIdx.x * 256 + wave * 64;  // first edge row

    // B fragments: B[k][c] = We[c][k]; lane holds col=ct*16+l15, k=kt*32+lhi*8 .. +7
    short8 Bf[2][4];
    #pragma unroll
    for (int kt = 0; kt < 2; ++kt)
        #pragma unroll
        for (int ct = 0; ct < 4; ++ct) {
            int c   = ct * 16 + l15;
            int k0i = kt * 32 + lhi * 8;
            Bf[kt][ct] = *reinterpret_cast<const short8*>(Web + c * kEdgeIn + k0i);
        }

    f32x4 acc[4][4];
    #pragma unroll
    for (int m = 0; m < 4; ++m)
        #pragma unroll
        for (int n = 0; n < 4; ++n) acc[m][n] = (f32x4)(0.f);

    #pragma unroll
    for (int m = 0; m < 4; ++m) {
        const float* erow = e + (base + m * 16 + l15) * kEdgeIn;
        #pragma unroll
        for (int kt = 0; kt < 2; ++kt) {
            const int k0i = kt * 32 + lhi * 8;
            float4 t0 = *reinterpret_cast<const float4*>(erow + k0i);
            float4 t1 = *reinterpret_cast<const float4*>(erow + k0i + 4);
            short8 af;
            af[0] = f2bf(t0.x); af[1] = f2bf(t0.y); af[2] = f2bf(t0.z); af[3] = f2bf(t0.w);
            af[4] = f2bf(t1.x); af[5] = f2bf(t1.y); af[6] = f2bf(t1.z); af[7] = f2bf(t1.w);
            #pragma unroll
            for (int ct = 0; ct < 4; ++ct)
                acc[m][ct] = __builtin_amdgcn_mfma_f32_16x16x32_bf16(
                    af, Bf[kt][ct], acc[m][ct], 0, 0, 0);
        }
    }

    // Epilogue: D col = l15, row = lhi*4 + reg. Scale by gamma[row], store.
    #pragma unroll
    for (int m = 0; m < 4; ++m) {
        const long r0 = base + m * 16 + lhi * 4;
        f32x4 g = *reinterpret_cast<const f32x4*>(gamma + r0);
        #pragma unroll
        for (int reg = 0; reg < 4; ++reg) {
            float gv = g[reg];
            #pragma unroll
            for (int ct = 0; ct < 4; ++ct)
                oute[(r0 + reg) * kEdgeOut + ct * 16 + l15] = acc[m][ct][reg] * gv;
        }
    }
}

extern "C" void kernel_launch(void* const* d_in, const int* in_sizes, int n_in,
                              void* d_out, int out_size, void* d_ws, size_t ws_size,
                              hipStream_t stream) {
    const float* h   = (const float*)d_in[0];
    const float* e   = (const float*)d_in[1];
    const float* Wn  = (const float*)d_in[2];
    const float* We  = (const float*)d_in[3];
    const float* Wa  = (const float*)d_in[4];
    const int*   src = (const int*)d_in[5];

    float* node_feat = (float*)d_out;
    float* oute      = (float*)d_out + (size_t)kNodes * kNodeOut;

    float* ws    = (float*)d_ws;
    float* v     = ws + kOffV;
    float* s_n   = ws + kOffSn;
    float* denom = ws + kOffDenom;
    float* ex    = ws + kOffEx;
    short* Web   = (short*)(ws + kOffWeB);

    k0_prep<<<1, 256, 0, stream>>>(We, Wa, v, Web);
    k1_nodes<<<(kNodes + 255) / 256, 256, 0, stream>>>(h, Wn, Wa, node_feat, s_n, denom);
    k2_logits<<<kEdges / 256, 256, 0, stream>>>(e, src, v, s_n, denom, ex);
    k3_gamma<<<kEdges / 256, 256, 0, stream>>>(src, denom, ex);
    k4_mfma<<<kEdges / 256, 256, 0, stream>>>(e, Web, ex, oute);
}

// Round 3
// 189.530 us; speedup vs baseline: 2.3818x; 1.5324x over previous
//
#include <hip/hip_runtime.h>

// WeightedAggEdge: node_feat = h@Wn^T; per-edge segment-softmax attention
// over fc_e(e) grouped by src node; outputs (node_feat, gamma * e_w).
//
// Algebraic restructure:
//   logit a_i = dot(e_i, v) + s_n[src_i],  v = We^T @ Wa[:,0:64],
//   s_n[n] = dot(Wa[:,64:128], node_feat[n])
//   gamma_i = exp(lr_i) / denom[src_i]  (shift-invariant, no segment-max pass)
//   node_feat and e_weighted both via bf16 16x16x32 MFMA (threshold 1.08e-1)

constexpr int kNodes   = 50000;
constexpr int kEdges   = 800000;
constexpr int kNodeIn  = 128;
constexpr int kNodeOut = 64;
constexpr int kEdgeIn  = 64;
constexpr int kEdgeOut = 64;
#define NEG_SLOPE 0.01f

typedef __attribute__((ext_vector_type(8))) short short8;   // 8 bf16 = 4 VGPRs
typedef __attribute__((ext_vector_type(4))) float f32x4;

// ws layout (float index):
//   [0, 64)              v = We^T @ Wa_e
//   [64, 50064)          s_n
//   [50064, 100064)      denom
//   [100064, 900064)     ex  (exp of leaky logit; k4 divides by denom on the fly)
//   [900064, +2048)      We_bf16 (4096 shorts, row-major [out][in])
//   [902112, +4096)      Wn_bf16 (8192 shorts, row-major [out][in])
constexpr int kOffV     = 0;
constexpr int kOffSn    = 64;
constexpr int kOffDenom = 50064;
constexpr int kOffEx    = 100064;
constexpr int kOffWeB   = 900064;
constexpr int kOffWnB   = 902112;

__device__ inline short f2bf(float x) {
    union { float f; unsigned u; } v; v.f = x;
    unsigned r = v.u + 0x7FFFu + ((v.u >> 16) & 1u);  // RNE
    return (short)(r >> 16);
}

__global__ void k0_prep(const float* __restrict__ We, const float* __restrict__ Wn,
                        const float* __restrict__ Wa,
                        float* __restrict__ v, short* __restrict__ Web,
                        short* __restrict__ Wnb) {
    int t = threadIdx.x;
    if (t < kEdgeIn) {
        float acc = 0.f;
        #pragma unroll
        for (int c = 0; c < kEdgeOut; ++c) acc = fmaf(Wa[c], We[c * kEdgeIn + t], acc);
        v[t] = acc;
    }
    #pragma unroll
    for (int i = 0; i < (kEdgeOut * kEdgeIn) / 256; ++i)
        Web[i * 256 + t] = f2bf(We[i * 256 + t]);
    #pragma unroll
    for (int i = 0; i < (kNodeOut * kNodeIn) / 256; ++i)
        Wnb[i * 256 + t] = f2bf(Wn[i * 256 + t]);
}

// node_feat = h @ Wn^T via bf16 MFMA; one wave = 16 nodes.
// Also: s_n[n] = dot(Wa[64:128], node_feat[n]) via 16-lane shfl reduce; denom init.
__global__ __launch_bounds__(256) void k1_mfma(
    const float* __restrict__ h, const short* __restrict__ Wnb,
    const float* __restrict__ Wa, float* __restrict__ node_feat,
    float* __restrict__ s_n, float* __restrict__ denom) {
    const int lane = threadIdx.x & 63;
    const int l15  = lane & 15;
    const int lhi  = lane >> 4;
    const int n0   = blockIdx.x * 64 + (threadIdx.x >> 6) * 16;

    int gid = blockIdx.x * 256 + threadIdx.x;
    if (gid < kNodes) denom[gid] = 0.f;

    // B fragments: Wn col c=ct*16+l15, k = kt*32 + lhi*8 .. +7
    short8 Bf[4][4];
    #pragma unroll
    for (int kt = 0; kt < 4; ++kt)
        #pragma unroll
        for (int ct = 0; ct < 4; ++ct)
            Bf[kt][ct] = *reinterpret_cast<const short8*>(
                Wnb + (ct * 16 + l15) * kNodeIn + kt * 32 + lhi * 8);

    const int  arow   = n0 + l15;
    const bool avalid = arow < kNodes;
    const float* hrow = h + (size_t)arow * kNodeIn;

    f32x4 acc[4];
    #pragma unroll
    for (int ct = 0; ct < 4; ++ct) acc[ct] = (f32x4)(0.f);

    #pragma unroll
    for (int kt = 0; kt < 4; ++kt) {
        short8 af;
        if (avalid) {
            float4 t0 = *reinterpret_cast<const float4*>(hrow + kt * 32 + lhi * 8);
            float4 t1 = *reinterpret_cast<const float4*>(hrow + kt * 32 + lhi * 8 + 4);
            af[0] = f2bf(t0.x); af[1] = f2bf(t0.y); af[2] = f2bf(t0.z); af[3] = f2bf(t0.w);
            af[4] = f2bf(t1.x); af[5] = f2bf(t1.y); af[6] = f2bf(t1.z); af[7] = f2bf(t1.w);
        } else {
            #pragma unroll
            for (int j = 0; j < 8; ++j) af[j] = 0;
        }
        #pragma unroll
        for (int ct = 0; ct < 4; ++ct)
            acc[ct] = __builtin_amdgcn_mfma_f32_16x16x32_bf16(af, Bf[kt][ct], acc[ct], 0, 0, 0);
    }

    // Epilogue: D col=l15 (+16*ct), row = n0 + lhi*4 + reg.
    float wa[4];
    #pragma unroll
    for (int ct = 0; ct < 4; ++ct) wa[ct] = Wa[64 + ct * 16 + l15];

    #pragma unroll
    for (int reg = 0; reg < 4; ++reg) {
        int r = n0 + lhi * 4 + reg;
        bool rv = r < kNodes;
        float part = 0.f;
        #pragma unroll
        for (int ct = 0; ct < 4; ++ct) part = fmaf(wa[ct], acc[ct][reg], part);
        if (rv) {
            #pragma unroll
            for (int ct = 0; ct < 4; ++ct)
                node_feat[(size_t)r * kNodeOut + ct * 16 + l15] = acc[ct][reg];
        }
        part += __shfl_xor(part, 1, 64);
        part += __shfl_xor(part, 2, 64);
        part += __shfl_xor(part, 4, 64);
        part += __shfl_xor(part, 8, 64);
        if (rv && l15 == 0) s_n[r] = part;
    }
}

__global__ __launch_bounds__(256) void k2_logits(
    const float* __restrict__ e, const int* __restrict__ src,
    const float* __restrict__ v, const float* __restrict__ s_n,
    float* __restrict__ denom, float* __restrict__ ex) {
    int i = blockIdx.x * 256 + threadIdx.x;
    if (i >= kEdges) return;
    const float4* e4 = reinterpret_cast<const float4*>(e + (size_t)i * kEdgeIn);
    float av = 0.f;
    #pragma unroll
    for (int q = 0; q < kEdgeIn / 4; ++q) {
        float4 t = e4[q];
        av = fmaf(t.x, v[4 * q],     av);
        av = fmaf(t.y, v[4 * q + 1], av);
        av = fmaf(t.z, v[4 * q + 2], av);
        av = fmaf(t.w, v[4 * q + 3], av);
    }
    int s = src[i];
    float a = av + s_n[s];
    float lr = (a >= 0.f) ? a : NEG_SLOPE * a;
    float xe = __expf(lr);
    ex[i] = xe;
    atomicAdd(denom + s, xe);
}

// e_weighted = (ex/denom[src]) * (e @ We^T) via bf16 MFMA; gamma fused in epilogue.
__global__ __launch_bounds__(256) void k4_mfma(
    const float* __restrict__ e, const short* __restrict__ Web,
    const int* __restrict__ src, const float* __restrict__ denom,
    const float* __restrict__ ex, float* __restrict__ oute) {
    const int wave = threadIdx.x >> 6;
    const int lane = threadIdx.x & 63;
    const int l15  = lane & 15;
    const int lhi  = lane >> 4;
    const long base = (long)blockIdx.x * 256 + wave * 64;  // first edge row

    short8 Bf[2][4];
    #pragma unroll
    for (int kt = 0; kt < 2; ++kt)
        #pragma unroll
        for (int ct = 0; ct < 4; ++ct)
            Bf[kt][ct] = *reinterpret_cast<const short8*>(
                Web + (ct * 16 + l15) * kEdgeIn + kt * 32 + lhi * 8);

    f32x4 acc[4][4];
    #pragma unroll
    for (int m = 0; m < 4; ++m)
        #pragma unroll
        for (int n = 0; n < 4; ++n) acc[m][n] = (f32x4)(0.f);

    #pragma unroll
    for (int m = 0; m < 4; ++m) {
        const float* erow = e + (base + m * 16 + l15) * kEdgeIn;
        #pragma unroll
        for (int kt = 0; kt < 2; ++kt) {
            const int k0i = kt * 32 + lhi * 8;
            float4 t0 = *reinterpret_cast<const float4*>(erow + k0i);
            float4 t1 = *reinterpret_cast<const float4*>(erow + k0i + 4);
            short8 af;
            af[0] = f2bf(t0.x); af[1] = f2bf(t0.y); af[2] = f2bf(t0.z); af[3] = f2bf(t0.w);
            af[4] = f2bf(t1.x); af[5] = f2bf(t1.y); af[6] = f2bf(t1.z); af[7] = f2bf(t1.w);
            #pragma unroll
            for (int ct = 0; ct < 4; ++ct)
                acc[m][ct] = __builtin_amdgcn_mfma_f32_16x16x32_bf16(
                    af, Bf[kt][ct], acc[m][ct], 0, 0, 0);
        }
    }

    // Epilogue: D col = ct*16+l15, row = lhi*4 + reg. gamma = ex * rcp(denom[src]).
    #pragma unroll
    for (int m = 0; m < 4; ++m) {
        const long r0 = base + m * 16 + lhi * 4;
        float4 exv = *reinterpret_cast<const float4*>(ex + r0);
        int4   sv  = *reinterpret_cast<const int4*>(src + r0);
        float ga[4];
        ga[0] = exv.x * __builtin_amdgcn_rcpf(denom[sv.x]);
        ga[1] = exv.y * __builtin_amdgcn_rcpf(denom[sv.y]);
        ga[2] = exv.z * __builtin_amdgcn_rcpf(denom[sv.z]);
        ga[3] = exv.w * __builtin_amdgcn_rcpf(denom[sv.w]);
        #pragma unroll
        for (int reg = 0; reg < 4; ++reg) {
            float gv = ga[reg];
            #pragma unroll
            for (int ct = 0; ct < 4; ++ct)
                oute[(r0 + reg) * kEdgeOut + ct * 16 + l15] = acc[m][ct][reg] * gv;
        }
    }
}

extern "C" void kernel_launch(void* const* d_in, const int* in_sizes, int n_in,
                              void* d_out, int out_size, void* d_ws, size_t ws_size,
                              hipStream_t stream) {
    const float* h   = (const float*)d_in[0];
    const float* e   = (const float*)d_in[1];
    const float* Wn  = (const float*)d_in[2];
    const float* We  = (const float*)d_in[3];
    const float* Wa  = (const float*)d_in[4];
    const int*   src = (const int*)d_in[5];

    float* node_feat = (float*)d_out;
    float* oute      = (float*)d_out + (size_t)kNodes * kNodeOut;

    float* ws    = (float*)d_ws;
    float* v     = ws + kOffV;
    float* s_n   = ws + kOffSn;
    float* denom = ws + kOffDenom;
    float* ex    = ws + kOffEx;
    short* Web   = (short*)(ws + kOffWeB);
    short* Wnb   = (short*)(ws + kOffWnB);

    k0_prep<<<1, 256, 0, stream>>>(We, Wn, Wa, v, Web, Wnb);
    k1_mfma<<<(kNodes + 63) / 64, 256, 0, stream>>>(h, Wnb, Wa, node_feat, s_n, denom);
    k2_logits<<<kEdges / 256, 256, 0, stream>>>(e, src, v, s_n, denom, ex);
    k4_mfma<<<kEdges / 256, 256, 0, stream>>>(e, Web, src, denom, ex, oute);
}